// Round 1
// baseline (3668.074 us; speedup 1.0000x reference)
//
#include <hip/hip_runtime.h>
#include <math.h>

#define BB 1024
#define TT 512
#define FF 32
#define HH 64
#define GG 256   // 4H
#define TC 64
#define NCHUNK (TT/TC)
#define EPSBN 1e-3f

// ---------------- fold1: per-layer BN vectors + attention vector ----------------
// s = gamma*rsqrt(var+eps); ab = beta - mean*s; wv' = s * (attw @ attv)
__global__ void fold1_kernel(const float* __restrict__ gamma, const float* __restrict__ beta,
                             const float* __restrict__ mean, const float* __restrict__ var,
                             const float* __restrict__ attw, const float* __restrict__ attv,
                             float* __restrict__ s_out, float* __restrict__ ab_out,
                             float* __restrict__ wv_out) {
    int d = threadIdx.x; // 64 threads
    float s = gamma[d] * rsqrtf(var[d] + EPSBN);
    float ab = beta[d] - mean[d] * s;
    float wvr = 0.f;
    for (int e = 0; e < HH; ++e) wvr += attw[d * HH + e] * attv[e];
    s_out[d] = s;
    ab_out[d] = ab;
    wv_out[d] = s * wvr;
}

// ---------------- fold2: fold previous layer's BN into next W, b ----------------
// W'[d][g] = s_prev[d]*W[d][g];  b'[g] = b[g] + sum_d ab_prev[d]*W[d][g]
__global__ void fold2_kernel(const float* __restrict__ W, const float* __restrict__ b,
                             const float* __restrict__ s_prev, const float* __restrict__ ab_prev,
                             float* __restrict__ Wp, float* __restrict__ bp) {
    int g = threadIdx.x; // 256 threads
    float bacc = b[g];
    for (int d = 0; d < HH; ++d) {
        float w = W[d * GG + g];
        bacc += ab_prev[d] * w;
        Wp[d * GG + g] = s_prev[d] * w;
    }
    bp[g] = bacc;
}

// ---------------- init per-call state (deterministic across replays) ----------------
__global__ void init_kernel(float* st_h, float* st_c, float* st_acc, float* st_m, float* st_d) {
    int i = blockIdx.x * blockDim.x + threadIdx.x;
    int n = 3 * BB * HH;
    if (i < n) { st_h[i] = 0.f; st_c[i] = 0.f; st_acc[i] = 0.f; }
    if (i < 3 * BB) { st_m[i] = -3.0e38f; st_d[i] = 0.f; }
}

// ---------------- xz GEMM: out[b][tt][g] = bias[g] + sum_k in[b][tt][k]*W[k][g] ----------------
// One block per batch row b; 64 rows (tt) per block; thread = output column g.
template<int K>
__global__ __launch_bounds__(256) void xz_gemm(const float* __restrict__ in, long strideB, long strideT,
                                               const float* __restrict__ Wt, const float* __restrict__ bias,
                                               float* __restrict__ out) {
    __shared__ float in_s[64 * K];
    int tid = threadIdx.x;
    int bid = blockIdx.x; // batch index
    const float* inb = in + (long)bid * strideB;
    constexpr int K4 = K / 4;
    constexpr int NF4 = 64 * K4;
    for (int f4 = tid; f4 < NF4; f4 += 256) {
        int r = f4 / K4, kk = (f4 % K4) * 4;
        float4 v = *reinterpret_cast<const float4*>(inb + (long)r * strideT + kk);
        *reinterpret_cast<float4*>(&in_s[r * K + kk]) = v;
    }
    float wreg[K];
#pragma unroll
    for (int k = 0; k < K; ++k) wreg[k] = Wt[k * GG + tid];
    float bg = bias[tid];
    __syncthreads();
    float* outb = out + (long)bid * (64 * GG);
    for (int r = 0; r < 64; ++r) {
        float acc = bg;
#pragma unroll
        for (int k4 = 0; k4 < K4; ++k4) {
            float4 h4 = *reinterpret_cast<const float4*>(&in_s[r * K + k4 * 4]);
            acc = fmaf(h4.x, wreg[k4 * 4 + 0], acc);
            acc = fmaf(h4.y, wreg[k4 * 4 + 1], acc);
            acc = fmaf(h4.z, wreg[k4 * 4 + 2], acc);
            acc = fmaf(h4.w, wreg[k4 * 4 + 3], acc);
        }
        outb[r * GG + tid] = acc;
    }
}

// ---------------- recurrent kernel: one T-chunk of the LSTM scan ----------------
// Block = 4 batch rows, 256 threads. GEMM phase: thread owns column g for all 4 rows.
// Update phase: thread (wave=row b, lane=j). Online-softmax attention fused.
__global__ __launch_bounds__(256) void rec_kernel(
    const float* __restrict__ xz,   // [B][TC][256]
    const float* __restrict__ U,    // [64][256]
    float* __restrict__ Hout,       // [B][TC][64]
    float* __restrict__ st_h, float* __restrict__ st_c,
    float* __restrict__ st_m, float* __restrict__ st_d, float* __restrict__ st_acc,
    const float* __restrict__ wv, const float* __restrict__ ab, const float* __restrict__ sbn,
    float* __restrict__ a_out,
    int last_chunk, int write_h) {
    __shared__ float4 h4v[HH];       // h[b0..b0+3][k] packed per k
    __shared__ float zs[4][GG];      // activated gates per row

    int tid = threadIdx.x;
    int b0 = blockIdx.x * 4;

    float u[HH];
#pragma unroll
    for (int k = 0; k < HH; ++k) u[k] = U[k * GG + tid];

    int ub = tid >> 6;   // wave id == local row
    int uj = tid & 63;   // lane == hidden unit
    float creg = st_c[(b0 + ub) * HH + uj];
    float hlast = st_h[(b0 + ub) * HH + uj];
    float accv = st_acc[(b0 + ub) * HH + uj];
    float m_b = st_m[b0 + ub];
    float d_b = st_d[b0 + ub];
    float wvj = wv[uj];

    reinterpret_cast<float*>(&h4v[uj])[ub] = hlast;
    __syncthreads();

    for (int t = 0; t < TC; ++t) {
        float xz0 = xz[((b0 + 0) * TC + t) * GG + tid];
        float xz1 = xz[((b0 + 1) * TC + t) * GG + tid];
        float xz2 = xz[((b0 + 2) * TC + t) * GG + tid];
        float xz3 = xz[((b0 + 3) * TC + t) * GG + tid];
        float a0 = 0.f, a1 = 0.f, a2 = 0.f, a3 = 0.f;
#pragma unroll
        for (int k = 0; k < HH; ++k) {
            float4 h4 = h4v[k];           // LDS broadcast (uniform address)
            a0 = fmaf(h4.x, u[k], a0);
            a1 = fmaf(h4.y, u[k], a1);
            a2 = fmaf(h4.z, u[k], a2);
            a3 = fmaf(h4.w, u[k], a3);
        }
        a0 += xz0; a1 += xz1; a2 += xz2; a3 += xz3;
        int gate = tid >> 6;  // wave-uniform: 0=i,1=f,2=g(relu),3=o
        if (gate == 2) {
            a0 = fmaxf(a0, 0.f); a1 = fmaxf(a1, 0.f);
            a2 = fmaxf(a2, 0.f); a3 = fmaxf(a3, 0.f);
        } else {
            a0 = __fdividef(1.f, 1.f + __expf(-a0));
            a1 = __fdividef(1.f, 1.f + __expf(-a1));
            a2 = __fdividef(1.f, 1.f + __expf(-a2));
            a3 = __fdividef(1.f, 1.f + __expf(-a3));
        }
        zs[0][tid] = a0; zs[1][tid] = a1; zs[2][tid] = a2; zs[3][tid] = a3;
        __syncthreads();

        // ---- update phase ----
        float zi = zs[ub][uj];
        float zf = zs[ub][64 + uj];
        float zg = zs[ub][128 + uj];
        float zo = zs[ub][192 + uj];
        creg = fmaf(zf, creg, zi * zg);
        float h = zo * fmaxf(creg, 0.f);
        hlast = h;

        // score = sum_j h*wv'  (wave butterfly reduce)
        float sc = h * wvj;
#pragma unroll
        for (int off = 1; off < 64; off <<= 1) sc += __shfl_xor(sc, off);
        // online softmax accumulation
        float mnew = fmaxf(m_b, sc);
        float corr = __expf(m_b - mnew);
        float p = __expf(sc - mnew);
        d_b = d_b * corr + p;
        accv = fmaf(accv, corr, p * h);
        m_b = mnew;

        reinterpret_cast<float*>(&h4v[uj])[ub] = h;
        if (write_h) Hout[((b0 + ub) * TC + t) * HH + uj] = h;
        __syncthreads();
    }

    st_c[(b0 + ub) * HH + uj] = creg;
    st_h[(b0 + ub) * HH + uj] = hlast;
    st_acc[(b0 + ub) * HH + uj] = accv;
    if (uj == 0) { st_m[b0 + ub] = m_b; st_d[b0 + ub] = d_b; }
    if (last_chunk) {
        a_out[(b0 + ub) * HH + uj] = sbn[uj] * __fdividef(accv, d_b) + ab[uj];
    }
}

// ---------------- final: out[b] = db + sum_{l,j} a[l][b][j]*dw[l*64+j] ----------------
__global__ void final_kernel(const float* __restrict__ a, const float* __restrict__ dw,
                             const float* __restrict__ db, float* __restrict__ out) {
    int b = blockIdx.x * blockDim.x + threadIdx.x;
    if (b >= BB) return;
    float acc = db[0];
    for (int l = 0; l < 3; ++l)
        for (int j = 0; j < HH; ++j)
            acc += a[(l * BB + b) * HH + j] * dw[l * HH + j];
    out[b] = acc;
}

extern "C" void kernel_launch(void* const* d_in, const int* in_sizes, int n_in,
                              void* d_out, int out_size, void* d_ws, size_t ws_size,
                              hipStream_t stream) {
    (void)in_sizes; (void)n_in; (void)out_size; (void)ws_size;
    const float* x = (const float*)d_in[0];
    const float* w[3]    = {(const float*)d_in[1],  (const float*)d_in[10], (const float*)d_in[19]};
    const float* uu[3]   = {(const float*)d_in[2],  (const float*)d_in[11], (const float*)d_in[20]};
    const float* bi[3]   = {(const float*)d_in[3],  (const float*)d_in[12], (const float*)d_in[21]};
    const float* gam[3]  = {(const float*)d_in[4],  (const float*)d_in[13], (const float*)d_in[22]};
    const float* bet[3]  = {(const float*)d_in[5],  (const float*)d_in[14], (const float*)d_in[23]};
    const float* mea[3]  = {(const float*)d_in[6],  (const float*)d_in[15], (const float*)d_in[24]};
    const float* var[3]  = {(const float*)d_in[7],  (const float*)d_in[16], (const float*)d_in[25]};
    const float* atw[3]  = {(const float*)d_in[8],  (const float*)d_in[17], (const float*)d_in[26]};
    const float* atv[3]  = {(const float*)d_in[9],  (const float*)d_in[18], (const float*)d_in[27]};
    const float* dw = (const float*)d_in[28];
    const float* db = (const float*)d_in[29];

    float* ws = (float*)d_ws;
    size_t off = 0;
    float* XZ    = ws + off; off += (size_t)BB * TC * GG;   // 16.78M
    float* Hbuf  = ws + off; off += (size_t)BB * TC * HH;   // 4.19M
    float* st_h  = ws + off; off += 3 * BB * HH;
    float* st_c  = ws + off; off += 3 * BB * HH;
    float* st_ac = ws + off; off += 3 * BB * HH;
    float* st_m  = ws + off; off += 3 * BB;
    float* st_d  = ws + off; off += 3 * BB;
    float* s_ws  = ws + off; off += 3 * HH;
    float* ab_ws = ws + off; off += 3 * HH;
    float* wv_ws = ws + off; off += 3 * HH;
    float* W2p   = ws + off; off += HH * GG;
    float* W3p   = ws + off; off += HH * GG;
    float* b2p   = ws + off; off += GG;
    float* b3p   = ws + off; off += GG;
    float* a_ws  = ws + off; off += 3 * BB * HH;

    // folds (recomputed every call: deterministic)
    for (int l = 0; l < 3; ++l)
        fold1_kernel<<<1, 64, 0, stream>>>(gam[l], bet[l], mea[l], var[l], atw[l], atv[l],
                                           s_ws + l * HH, ab_ws + l * HH, wv_ws + l * HH);
    fold2_kernel<<<1, 256, 0, stream>>>(w[1], bi[1], s_ws + 0 * HH, ab_ws + 0 * HH, W2p, b2p);
    fold2_kernel<<<1, 256, 0, stream>>>(w[2], bi[2], s_ws + 1 * HH, ab_ws + 1 * HH, W3p, b3p);
    init_kernel<<<(3 * BB * HH + 255) / 256, 256, 0, stream>>>(st_h, st_c, st_ac, st_m, st_d);

    for (int ch = 0; ch < NCHUNK; ++ch) {
        int last = (ch == NCHUNK - 1) ? 1 : 0;
        // layer 1 (input x, K=32, raw weights)
        xz_gemm<32><<<BB, 256, 0, stream>>>(x + (size_t)ch * TC * FF, (long)TT * FF, (long)FF,
                                            w[0], bi[0], XZ);
        rec_kernel<<<BB / 4, 256, 0, stream>>>(XZ, uu[0], Hbuf,
                                               st_h + 0 * BB * HH, st_c + 0 * BB * HH,
                                               st_m + 0 * BB, st_d + 0 * BB, st_ac + 0 * BB * HH,
                                               wv_ws + 0 * HH, ab_ws + 0 * HH, s_ws + 0 * HH,
                                               a_ws + 0 * BB * HH, last, 1);
        // layer 2 (input h1 raw, folded W')
        xz_gemm<64><<<BB, 256, 0, stream>>>(Hbuf, (long)TC * HH, (long)HH, W2p, b2p, XZ);
        rec_kernel<<<BB / 4, 256, 0, stream>>>(XZ, uu[1], Hbuf,
                                               st_h + 1 * BB * HH, st_c + 1 * BB * HH,
                                               st_m + 1 * BB, st_d + 1 * BB, st_ac + 1 * BB * HH,
                                               wv_ws + 1 * HH, ab_ws + 1 * HH, s_ws + 1 * HH,
                                               a_ws + 1 * BB * HH, last, 1);
        // layer 3 (h not needed downstream)
        xz_gemm<64><<<BB, 256, 0, stream>>>(Hbuf, (long)TC * HH, (long)HH, W3p, b3p, XZ);
        rec_kernel<<<BB / 4, 256, 0, stream>>>(XZ, uu[2], Hbuf,
                                               st_h + 2 * BB * HH, st_c + 2 * BB * HH,
                                               st_m + 2 * BB, st_d + 2 * BB, st_ac + 2 * BB * HH,
                                               wv_ws + 2 * HH, ab_ws + 2 * HH, s_ws + 2 * HH,
                                               a_ws + 2 * BB * HH, last, 0);
    }
    final_kernel<<<(BB + 255) / 256, 256, 0, stream>>>(a_ws, dw, db, (float*)d_out);
}

// Round 2
// 3005.391 us; speedup vs baseline: 1.2205x; 1.2205x over previous
//
#include <hip/hip_runtime.h>
#include <math.h>

#define BB 1024
#define TT 512
#define FF 32
#define HH 64
#define GG 256   // 4H
#define TC 64
#define NCHUNK (TT/TC)
#define EPSBN 1e-3f

// ---------------- fold1: per-layer BN vectors + attention vector ----------------
// s = gamma*rsqrt(var+eps); ab = beta - mean*s; wv' = s * (attw @ attv)
__global__ void fold1_kernel(const float* __restrict__ gamma, const float* __restrict__ beta,
                             const float* __restrict__ mean, const float* __restrict__ var,
                             const float* __restrict__ attw, const float* __restrict__ attv,
                             float* __restrict__ s_out, float* __restrict__ ab_out,
                             float* __restrict__ wv_out) {
    int d = threadIdx.x; // 64 threads
    float s = gamma[d] * rsqrtf(var[d] + EPSBN);
    float ab = beta[d] - mean[d] * s;
    float wvr = 0.f;
    for (int e = 0; e < HH; ++e) wvr += attw[d * HH + e] * attv[e];
    s_out[d] = s;
    ab_out[d] = ab;
    wv_out[d] = s * wvr;
}

// ---------------- fold2: fold previous layer's BN into next W, b ----------------
// W'[d][g] = s_prev[d]*W[d][g];  b'[g] = b[g] + sum_d ab_prev[d]*W[d][g]
__global__ void fold2_kernel(const float* __restrict__ W, const float* __restrict__ b,
                             const float* __restrict__ s_prev, const float* __restrict__ ab_prev,
                             float* __restrict__ Wp, float* __restrict__ bp) {
    int g = threadIdx.x; // 256 threads
    float bacc = b[g];
    for (int d = 0; d < HH; ++d) {
        float w = W[d * GG + g];
        bacc += ab_prev[d] * w;
        Wp[d * GG + g] = s_prev[d] * w;
    }
    bp[g] = bacc;
}

// ---------------- init per-call state (deterministic across replays) ----------------
__global__ void init_kernel(float* st_h, float* st_c, float* st_acc, float* st_m, float* st_d) {
    int i = blockIdx.x * blockDim.x + threadIdx.x;
    int n = 3 * BB * HH;
    if (i < n) { st_h[i] = 0.f; st_c[i] = 0.f; st_acc[i] = 0.f; }
    if (i < 3 * BB) { st_m[i] = -3.0e38f; st_d[i] = 0.f; }
}

// ---------------- xz GEMM: out[b][tt][g] = bias[g] + sum_k in[b][tt][k]*W[k][g] ----------------
template<int K>
__global__ __launch_bounds__(256) void xz_gemm(const float* __restrict__ in, long strideB, long strideT,
                                               const float* __restrict__ Wt, const float* __restrict__ bias,
                                               float* __restrict__ out) {
    __shared__ float in_s[64 * K];
    int tid = threadIdx.x;
    int bid = blockIdx.x; // batch index
    const float* inb = in + (long)bid * strideB;
    constexpr int K4 = K / 4;
    constexpr int NF4 = 64 * K4;
    for (int f4 = tid; f4 < NF4; f4 += 256) {
        int r = f4 / K4, kk = (f4 % K4) * 4;
        float4 v = *reinterpret_cast<const float4*>(inb + (long)r * strideT + kk);
        *reinterpret_cast<float4*>(&in_s[r * K + kk]) = v;
    }
    float wreg[K];
#pragma unroll
    for (int k = 0; k < K; ++k) wreg[k] = Wt[k * GG + tid];
    float bg = bias[tid];
    __syncthreads();
    float* outb = out + (long)bid * (64 * GG);
    for (int r = 0; r < 64; ++r) {
        float acc = bg;
#pragma unroll
        for (int k4 = 0; k4 < K4; ++k4) {
            float4 h4 = *reinterpret_cast<const float4*>(&in_s[r * K + k4 * 4]);
            acc = fmaf(h4.x, wreg[k4 * 4 + 0], acc);
            acc = fmaf(h4.y, wreg[k4 * 4 + 1], acc);
            acc = fmaf(h4.z, wreg[k4 * 4 + 2], acc);
            acc = fmaf(h4.w, wreg[k4 * 4 + 3], acc);
        }
        outb[r * GG + tid] = acc;
    }
}

// ---------------- recurrent kernel: barrier-free, one wave per batch row ----------------
// Lane j owns hidden unit j and all 4 gate columns of U. h-broadcast via v_readlane
// (VALU, no LDS, no barriers). Attention (online softmax) fused; its shuffle
// reduce is off the recurrence critical path.
__global__ __launch_bounds__(64, 1) void rec_kernel(
    const float* __restrict__ xz,   // [B][TC][256]
    const float* __restrict__ U,    // [64][256]
    float* __restrict__ Hout,       // [B][TC][64]
    float* __restrict__ st_h, float* __restrict__ st_c,
    float* __restrict__ st_m, float* __restrict__ st_d, float* __restrict__ st_acc,
    const float* __restrict__ wv, const float* __restrict__ ab, const float* __restrict__ sbn,
    float* __restrict__ a_out,
    int last_chunk, int write_h) {
    int j = threadIdx.x;   // hidden unit
    int b = blockIdx.x;    // batch row

    float ui[HH], uf[HH], ug[HH], uo[HH];
#pragma unroll
    for (int k = 0; k < HH; ++k) {
        const float* Uk = U + k * GG;
        ui[k] = Uk[j];
        uf[k] = Uk[64 + j];
        ug[k] = Uk[128 + j];
        uo[k] = Uk[192 + j];
    }

    float c    = st_c[b * HH + j];
    float h    = st_h[b * HH + j];
    float accv = st_acc[b * HH + j];
    float m_b  = st_m[b];
    float d_b  = st_d[b];
    float wvj  = wv[j];

    const float* xzb = xz + (size_t)b * TC * GG;
    float x_i = xzb[j], x_f = xzb[64 + j], x_g = xzb[128 + j], x_o = xzb[192 + j];

    for (int t = 0; t < TC; ++t) {
        // prefetch next timestep's xz (clamped; redundant last load is harmless)
        int tn = (t + 1 < TC) ? (t + 1) : (TC - 1);
        const float* p = xzb + tn * GG;
        float nx_i = p[j], nx_f = p[64 + j], nx_g = p[128 + j], nx_o = p[192 + j];

        float ai = x_i, af = x_f, ag = x_g, ao = x_o;
        int hbits = __float_as_int(h);
#pragma unroll
        for (int k = 0; k < HH; ++k) {
            float hk = __int_as_float(__builtin_amdgcn_readlane(hbits, k));
            ai = fmaf(hk, ui[k], ai);
            af = fmaf(hk, uf[k], af);
            ag = fmaf(hk, ug[k], ag);
            ao = fmaf(hk, uo[k], ao);
        }
        float gi = __fdividef(1.f, 1.f + __expf(-ai));
        float gf = __fdividef(1.f, 1.f + __expf(-af));
        float gg = fmaxf(ag, 0.f);
        float go = __fdividef(1.f, 1.f + __expf(-ao));
        c = fmaf(gf, c, gi * gg);
        h = go * fmaxf(c, 0.f);
        if (write_h) Hout[((size_t)b * TC + t) * HH + j] = h;

        // attention score: full-wave reduce (off the recurrence critical path)
        float sc = h * wvj;
#pragma unroll
        for (int off = 1; off < 64; off <<= 1) sc += __shfl_xor(sc, off);
        float mnew = fmaxf(m_b, sc);
        float corr = __expf(m_b - mnew);
        float pr = __expf(sc - mnew);
        d_b = d_b * corr + pr;
        accv = fmaf(accv, corr, pr * h);
        m_b = mnew;

        x_i = nx_i; x_f = nx_f; x_g = nx_g; x_o = nx_o;
    }

    st_c[b * HH + j] = c;
    st_h[b * HH + j] = h;
    st_acc[b * HH + j] = accv;
    if (j == 0) { st_m[b] = m_b; st_d[b] = d_b; }
    if (last_chunk) {
        a_out[b * HH + j] = sbn[j] * __fdividef(accv, d_b) + ab[j];
    }
}

// ---------------- final: out[b] = db + sum_{l,j} a[l][b][j]*dw[l*64+j] ----------------
__global__ void final_kernel(const float* __restrict__ a, const float* __restrict__ dw,
                             const float* __restrict__ db, float* __restrict__ out) {
    int b = blockIdx.x * blockDim.x + threadIdx.x;
    if (b >= BB) return;
    float acc = db[0];
    for (int l = 0; l < 3; ++l)
        for (int j = 0; j < HH; ++j)
            acc += a[(l * BB + b) * HH + j] * dw[l * HH + j];
    out[b] = acc;
}

extern "C" void kernel_launch(void* const* d_in, const int* in_sizes, int n_in,
                              void* d_out, int out_size, void* d_ws, size_t ws_size,
                              hipStream_t stream) {
    (void)in_sizes; (void)n_in; (void)out_size; (void)ws_size;
    const float* x = (const float*)d_in[0];
    const float* w[3]    = {(const float*)d_in[1],  (const float*)d_in[10], (const float*)d_in[19]};
    const float* uu[3]   = {(const float*)d_in[2],  (const float*)d_in[11], (const float*)d_in[20]};
    const float* bi[3]   = {(const float*)d_in[3],  (const float*)d_in[12], (const float*)d_in[21]};
    const float* gam[3]  = {(const float*)d_in[4],  (const float*)d_in[13], (const float*)d_in[22]};
    const float* bet[3]  = {(const float*)d_in[5],  (const float*)d_in[14], (const float*)d_in[23]};
    const float* mea[3]  = {(const float*)d_in[6],  (const float*)d_in[15], (const float*)d_in[24]};
    const float* var[3]  = {(const float*)d_in[7],  (const float*)d_in[16], (const float*)d_in[25]};
    const float* atw[3]  = {(const float*)d_in[8],  (const float*)d_in[17], (const float*)d_in[26]};
    const float* atv[3]  = {(const float*)d_in[9],  (const float*)d_in[18], (const float*)d_in[27]};
    const float* dw = (const float*)d_in[28];
    const float* db = (const float*)d_in[29];

    float* ws = (float*)d_ws;
    size_t off = 0;
    float* XZ    = ws + off; off += (size_t)BB * TC * GG;   // 16.78M
    float* Hbuf  = ws + off; off += (size_t)BB * TC * HH;   // 4.19M
    float* st_h  = ws + off; off += 3 * BB * HH;
    float* st_c  = ws + off; off += 3 * BB * HH;
    float* st_ac = ws + off; off += 3 * BB * HH;
    float* st_m  = ws + off; off += 3 * BB;
    float* st_d  = ws + off; off += 3 * BB;
    float* s_ws  = ws + off; off += 3 * HH;
    float* ab_ws = ws + off; off += 3 * HH;
    float* wv_ws = ws + off; off += 3 * HH;
    float* W2p   = ws + off; off += HH * GG;
    float* W3p   = ws + off; off += HH * GG;
    float* b2p   = ws + off; off += GG;
    float* b3p   = ws + off; off += GG;
    float* a_ws  = ws + off; off += 3 * BB * HH;

    for (int l = 0; l < 3; ++l)
        fold1_kernel<<<1, 64, 0, stream>>>(gam[l], bet[l], mea[l], var[l], atw[l], atv[l],
                                           s_ws + l * HH, ab_ws + l * HH, wv_ws + l * HH);
    fold2_kernel<<<1, 256, 0, stream>>>(w[1], bi[1], s_ws + 0 * HH, ab_ws + 0 * HH, W2p, b2p);
    fold2_kernel<<<1, 256, 0, stream>>>(w[2], bi[2], s_ws + 1 * HH, ab_ws + 1 * HH, W3p, b3p);
    init_kernel<<<(3 * BB * HH + 255) / 256, 256, 0, stream>>>(st_h, st_c, st_ac, st_m, st_d);

    for (int ch = 0; ch < NCHUNK; ++ch) {
        int last = (ch == NCHUNK - 1) ? 1 : 0;
        // layer 1 (input x, K=32, raw weights)
        xz_gemm<32><<<BB, 256, 0, stream>>>(x + (size_t)ch * TC * FF, (long)TT * FF, (long)FF,
                                            w[0], bi[0], XZ);
        rec_kernel<<<BB, 64, 0, stream>>>(XZ, uu[0], Hbuf,
                                          st_h + 0 * BB * HH, st_c + 0 * BB * HH,
                                          st_m + 0 * BB, st_d + 0 * BB, st_ac + 0 * BB * HH,
                                          wv_ws + 0 * HH, ab_ws + 0 * HH, s_ws + 0 * HH,
                                          a_ws + 0 * BB * HH, last, 1);
        // layer 2 (input h1, folded W')
        xz_gemm<64><<<BB, 256, 0, stream>>>(Hbuf, (long)TC * HH, (long)HH, W2p, b2p, XZ);
        rec_kernel<<<BB, 64, 0, stream>>>(XZ, uu[1], Hbuf,
                                          st_h + 1 * BB * HH, st_c + 1 * BB * HH,
                                          st_m + 1 * BB, st_d + 1 * BB, st_ac + 1 * BB * HH,
                                          wv_ws + 1 * HH, ab_ws + 1 * HH, s_ws + 1 * HH,
                                          a_ws + 1 * BB * HH, last, 1);
        // layer 3 (h not needed downstream)
        xz_gemm<64><<<BB, 256, 0, stream>>>(Hbuf, (long)TC * HH, (long)HH, W3p, b3p, XZ);
        rec_kernel<<<BB, 64, 0, stream>>>(XZ, uu[2], Hbuf,
                                          st_h + 2 * BB * HH, st_c + 2 * BB * HH,
                                          st_m + 2 * BB, st_d + 2 * BB, st_ac + 2 * BB * HH,
                                          wv_ws + 2 * HH, ab_ws + 2 * HH, s_ws + 2 * HH,
                                          a_ws + 2 * BB * HH, last, 0);
    }
    final_kernel<<<(BB + 255) / 256, 256, 0, stream>>>(a_ws, dw, db, (float*)d_out);
}